// Round 1
// baseline (74.678 us; speedup 1.0000x reference)
//
#include <hip/hip_runtime.h>

#define BB 8
#define NN 256
#define DD 128
#define SW 257  // W_msg row stride (2D+1)
#define SU 256  // W_upd row stride (2D)

__device__ __forceinline__ float wave_reduce_add(float v) {
#pragma unroll
  for (int off = 32; off > 0; off >>= 1) v += __shfl_xor(v, off, 64);
  return v;
}

__device__ __forceinline__ float silu_f(float y) {
  // y * sigmoid(y) = y / (1 + exp(-y))
  return y * __builtin_amdgcn_rcpf(1.0f + __expf(-y));
}

// ---------------- K1: u = h@Wt^T + b_msg, s = h@Ws^T, plus row means -------
__global__ __launch_bounds__(128) void k_proj(
    const float* __restrict__ h, const float* __restrict__ Wm,
    const float* __restrict__ bmsg,
    float* __restrict__ u, float* __restrict__ s,
    float* __restrict__ muu, float* __restrict__ mus) {
  const int blk = blockIdx.x;            // 256 blocks: 32 per batch, 8 rows each
  const int b = blk >> 5;
  const int r0 = (blk & 31) * 8;
  const int e = threadIdx.x;             // 0..127 (output channel)
  const int lane = e & 63, wv = e >> 6;

  __shared__ float hs[8][DD];
  const float* hb = h + (size_t)(b * NN + r0) * DD;
#pragma unroll
  for (int k = 0; k < 8; ++k) hs[k][e] = hb[k * DD + e];
  __syncthreads();

  float au[8], as_[8];
#pragma unroll
  for (int k = 0; k < 8; ++k) { au[k] = 0.f; as_[k] = 0.f; }

  const float* wr = Wm + (size_t)e * SW;
  for (int d = 0; d < DD; d += 4) {
    const float4 wt  = *(const float4*)(wr + d);
    const float4 wsv = *(const float4*)(wr + DD + d);
#pragma unroll
    for (int k = 0; k < 8; ++k) {
      const float4 hv = *(const float4*)(&hs[k][d]);
      au[k]  = fmaf(hv.x, wt.x,  au[k]);  au[k]  = fmaf(hv.y, wt.y,  au[k]);
      au[k]  = fmaf(hv.z, wt.z,  au[k]);  au[k]  = fmaf(hv.w, wt.w,  au[k]);
      as_[k] = fmaf(hv.x, wsv.x, as_[k]); as_[k] = fmaf(hv.y, wsv.y, as_[k]);
      as_[k] = fmaf(hv.z, wsv.z, as_[k]); as_[k] = fmaf(hv.w, wsv.w, as_[k]);
    }
  }

  const float bm = bmsg[e];
  __shared__ float pu[2][8], ps[2][8];
  float* uo = u + (size_t)(b * NN + r0) * DD;
  float* so = s + (size_t)(b * NN + r0) * DD;
#pragma unroll
  for (int k = 0; k < 8; ++k) {
    const float vu = au[k] + bm;         // fold b_msg into u
    uo[k * DD + e] = vu;
    so[k * DD + e] = as_[k];
    const float su = wave_reduce_add(vu);
    const float ss = wave_reduce_add(as_[k]);
    if (lane == 0) { pu[wv][k] = su; ps[wv][k] = ss; }
  }
  __syncthreads();
  if (e < 8) {
    muu[b * NN + r0 + e] = (pu[0][e] + pu[1][e]) * (1.0f / DD);
    mus[b * NN + r0 + e] = (ps[0][e] + ps[1][e]) * (1.0f / DD);
  }
}

// ---------------- K2: fused message LN+SiLU+aggregate ----------------------
// One block per (b,i). 4 waves; wave w handles j = w, w+4, ...
// mean decomposes exactly: mean = mu_u[i] + mu_s[j] + aJ*mu_w  -> only the
// variance needs a cross-lane butterfly (1 value, 6 steps).
__global__ __launch_bounds__(256) void k_msg(
    const float* __restrict__ u, const float* __restrict__ s,
    const float* __restrict__ muu, const float* __restrict__ mus,
    const float* __restrict__ adj, const float* __restrict__ Wm,
    const float* __restrict__ g, const float* __restrict__ be,
    float* __restrict__ agg) {
  const int blk = blockIdx.x;            // 2048 = b*256 + i
  const int b = blk >> 8, i = blk & 255;
  const int tid = threadIdx.x, lane = tid & 63, wv = tid >> 6;

  __shared__ float s_adj[NN], s_mus[NN];
  s_adj[tid] = adj[(size_t)blk * NN + tid];
  s_mus[tid] = mus[b * NN + tid];
  __syncthreads();

  const float u0 = u[(size_t)blk * DD + lane];
  const float u1 = u[(size_t)blk * DD + lane + 64];
  const float w0 = Wm[lane * SW + 2 * DD];
  const float w1 = Wm[(lane + 64) * SW + 2 * DD];
  const float g0 = g[lane],  g1 = g[lane + 64];
  const float be0 = be[lane], be1 = be[lane + 64];
  const float mu_i = muu[blk];
  const float mu_w = wave_reduce_add(w0 + w1) * (1.0f / DD);

  float acc0 = 0.f, acc1 = 0.f;
  const float* srow = s + (size_t)b * NN * DD;
  for (int j = wv; j < NN; j += 4) {
    if (j == i) continue;                // wave-uniform scalar branch
    const float aJ = s_adj[j];
    const float mean = fmaf(aJ, mu_w, mu_i + s_mus[j]);
    const float s0 = srow[j * DD + lane];
    const float s1 = srow[j * DD + lane + 64];
    const float x0 = fmaf(aJ, w0, (u0 - mean) + s0);   // centered pre
    const float x1 = fmaf(aJ, w1, (u1 - mean) + s1);
    float q = fmaf(x1, x1, x0 * x0);
    q = wave_reduce_add(q);                            // sum of squares, 128 elems
    const float rs = __builtin_amdgcn_rsqf(q * (1.0f / DD) + 1e-5f);
    const float y0 = fmaf(x0 * rs, g0, be0);
    const float y1 = fmaf(x1 * rs, g1, be1);
    acc0 = fmaf(y0, __builtin_amdgcn_rcpf(1.0f + __expf(-y0)), acc0);
    acc1 = fmaf(y1, __builtin_amdgcn_rcpf(1.0f + __expf(-y1)), acc1);
  }

  __shared__ float sacc[4][DD];
  sacc[wv][lane] = acc0;
  sacc[wv][lane + 64] = acc1;
  __syncthreads();
  if (tid < DD) {
    agg[(size_t)blk * DD + tid] =
        sacc[0][tid] + sacc[1][tid] + sacc[2][tid] + sacc[3][tid];
  }
}

// ---------------- K3: update GEMM + LN + SiLU + residual -------------------
__global__ __launch_bounds__(128) void k_upd(
    const float* __restrict__ h, const float* __restrict__ agg,
    const float* __restrict__ Wu, const float* __restrict__ bu,
    const float* __restrict__ gu, const float* __restrict__ beu,
    float* __restrict__ out) {
  const int blk = blockIdx.x;            // 256 blocks, 8 rows each
  const int b = blk >> 5;
  const int r0 = (blk & 31) * 8;
  const int e = threadIdx.x;             // output channel
  const int lane = e & 63, wv = e >> 6;

  __shared__ float hs[8][DD], ags[8][DD];
  const size_t base = (size_t)(b * NN + r0) * DD;
#pragma unroll
  for (int k = 0; k < 8; ++k) {
    hs[k][e]  = h[base + k * DD + e];
    ags[k][e] = agg[base + k * DD + e];
  }
  __syncthreads();

  float acc[8];
  const float b0 = bu[e];
#pragma unroll
  for (int k = 0; k < 8; ++k) acc[k] = b0;

  const float* wr = Wu + (size_t)e * SU;
  for (int d = 0; d < DD; d += 4) {
    const float4 w1 = *(const float4*)(wr + d);
    const float4 w2 = *(const float4*)(wr + DD + d);
#pragma unroll
    for (int k = 0; k < 8; ++k) {
      const float4 hv = *(const float4*)(&hs[k][d]);
      const float4 av = *(const float4*)(&ags[k][d]);
      acc[k] = fmaf(hv.x, w1.x, acc[k]); acc[k] = fmaf(hv.y, w1.y, acc[k]);
      acc[k] = fmaf(hv.z, w1.z, acc[k]); acc[k] = fmaf(hv.w, w1.w, acc[k]);
      acc[k] = fmaf(av.x, w2.x, acc[k]); acc[k] = fmaf(av.y, w2.y, acc[k]);
      acc[k] = fmaf(av.z, w2.z, acc[k]); acc[k] = fmaf(av.w, w2.w, acc[k]);
    }
  }

  const float ge = gu[e], bee = beu[e];
  __shared__ float part[2][2];
  for (int k = 0; k < 8; ++k) {
    const float v = acc[k];
    const float sm = wave_reduce_add(v);
    const float sq = wave_reduce_add(v * v);
    if (lane == 0) { part[wv][0] = sm; part[wv][1] = sq; }
    __syncthreads();
    const float S = part[0][0] + part[1][0];
    const float Q = part[0][1] + part[1][1];
    __syncthreads();
    const float mean = S * (1.0f / DD);
    const float var = Q * (1.0f / DD) - mean * mean;
    const float rs = __builtin_amdgcn_rsqf(var + 1e-5f);
    const float y = fmaf((v - mean) * rs, ge, bee);
    out[base + k * DD + e] = hs[k][e] + silu_f(y);
  }
}

extern "C" void kernel_launch(void* const* d_in, const int* in_sizes, int n_in,
                              void* d_out, int out_size, void* d_ws, size_t ws_size,
                              hipStream_t stream) {
  const float* h    = (const float*)d_in[0];
  const float* adj  = (const float*)d_in[1];
  const float* Wm   = (const float*)d_in[2];
  const float* bmsg = (const float*)d_in[3];
  const float* gmsg = (const float*)d_in[4];
  const float* bemsg= (const float*)d_in[5];
  const float* Wu   = (const float*)d_in[6];
  const float* bupd = (const float*)d_in[7];
  const float* gupd = (const float*)d_in[8];
  const float* beupd= (const float*)d_in[9];
  float* out = (float*)d_out;

  // workspace layout (floats)
  float* ws   = (float*)d_ws;
  float* u    = ws;                       // 2048*128
  float* s    = u + BB * NN * DD;         // 2048*128
  float* aggp = s + BB * NN * DD;         // 2048*128
  float* muu  = aggp + BB * NN * DD;      // 2048
  float* mus  = muu + BB * NN;            // 2048

  k_proj<<<BB * NN / 8, 128, 0, stream>>>(h, Wm, bmsg, u, s, muu, mus);
  k_msg<<<BB * NN, 256, 0, stream>>>(u, s, muu, mus, adj, Wm, gmsg, bemsg, aggp);
  k_upd<<<BB * NN / 8, 128, 0, stream>>>(h, aggp, Wu, bupd, gupd, beupd, out);
}